// Round 4
// baseline (96.794 us; speedup 1.0000x reference)
//
#include <hip/hip_runtime.h>

#define NC 14
#define DIM 96
#define NV (DIM*DIM*DIM)       // 884736
#define NV8 (NV/8)             // 110592
// padded mask volume: [ph 98][pw 98][pd 112], voxel (h,w,d) -> (h+1, w+1, d+8)
#define WS2 112
#define HS2 (112*98)           // 10976
#define PADV (112*98*98)       // 1075648 elements per batch
#define SLABB ((size_t)PADV*2*2)   // bytes for 2 batches of ushort

// ---- Kernel 1: argmax over classes, 8 voxels/thread -> bitmask ushort8 ----
__global__ void __launch_bounds__(128)
argmax_bit_kernel(const float* __restrict__ outT, unsigned short* __restrict__ bm) {
    int tid = blockIdx.x * 128 + threadIdx.x;       // < 2*NV8
    int b = tid >= NV8;
    int q = tid - b * NV8;
    int v8 = q * 8;
    const float* p = outT + (size_t)b * NC * NV + v8;
    float4 a0 = *(const float4*)p;
    float4 a1 = *(const float4*)(p + 4);
    float bv[8] = {a0.x, a0.y, a0.z, a0.w, a1.x, a1.y, a1.z, a1.w};
    int bi[8] = {0, 0, 0, 0, 0, 0, 0, 0};
#pragma unroll
    for (int c = 1; c < NC; ++c) {
        float4 v0 = *(const float4*)(p + (size_t)c * NV);
        float4 v1 = *(const float4*)(p + (size_t)c * NV + 4);
        float vv[8] = {v0.x, v0.y, v0.z, v0.w, v1.x, v1.y, v1.z, v1.w};
#pragma unroll
        for (int j = 0; j < 8; ++j)
            if (vv[j] > bv[j]) { bv[j] = vv[j]; bi[j] = c; }
    }
    int d = v8 % DIM;
    int t1 = v8 / DIM;
    int w = t1 % DIM;
    int h = t1 / DIM;
    uint4 out;
    out.x = (1u << bi[0]) | ((1u << bi[1]) << 16);
    out.y = (1u << bi[2]) | ((1u << bi[3]) << 16);
    out.z = (1u << bi[4]) | ((1u << bi[5]) << 16);
    out.w = (1u << bi[6]) | ((1u << bi[7]) << 16);
    *(uint4*)(bm + (size_t)b * PADV + (h + 1) * HS2 + (w + 1) * WS2 + (d + 8)) = out;
}

// ---- Kernel 2: OR along d, 8 elems/thread ----
__global__ void __launch_bounds__(256)
or_d_kernel(const unsigned short* __restrict__ bm, unsigned short* __restrict__ dm) {
    int idx = blockIdx.x * 256 + threadIdx.x;
    if (idx >= 2 * PADV / 8) return;
    int base = idx * 8;
    int pd0 = base % WS2;
    if (pd0 == 0 || pd0 == 104) return;             // outputs only pd in [8,103]
    uint4 X = *(const uint4*)(bm + base);
    unsigned short xm1 = bm[base - 1];
    unsigned short xp8 = bm[base + 8];
    unsigned x[10];
    x[0] = xm1;
    x[1] = X.x & 0xFFFFu; x[2] = X.x >> 16;
    x[3] = X.y & 0xFFFFu; x[4] = X.y >> 16;
    x[5] = X.z & 0xFFFFu; x[6] = X.z >> 16;
    x[7] = X.w & 0xFFFFu; x[8] = X.w >> 16;
    x[9] = xp8;
    unsigned r[8];
#pragma unroll
    for (int j = 0; j < 8; ++j) r[j] = x[j] | x[j + 1] | x[j + 2];
    uint4 out;
    out.x = r[0] | (r[1] << 16);
    out.y = r[2] | (r[3] << 16);
    out.z = r[4] | (r[5] << 16);
    out.w = r[6] | (r[7] << 16);
    *(uint4*)(dm + base) = out;
}

// ---- Kernel 3: OR along w, pure uint4, 8 elems/thread ----
__global__ void __launch_bounds__(256)
or_w_kernel(const unsigned short* __restrict__ dm, unsigned short* __restrict__ wm) {
    int idx = blockIdx.x * 256 + threadIdx.x;
    if (idx >= 2 * PADV / 8) return;
    int base = idx * 8;
    int pw = ((base % PADV) / WS2) % 98;
    if (pw < 1 || pw > 96) return;
    uint4 a = *(const uint4*)(dm + base - WS2);
    uint4 c = *(const uint4*)(dm + base);
    uint4 e = *(const uint4*)(dm + base + WS2);
    uint4 out;
    out.x = a.x | c.x | e.x;
    out.y = a.y | c.y | e.y;
    out.z = a.z | c.z | e.z;
    out.w = a.w | c.w | e.w;
    *(uint4*)(wm + base) = out;
}

// ---- Kernel 4: h-OR + KL + accumulation, 8 voxels/thread ----
__global__ void __launch_bounds__(128)
boundary_kl_kernel(const float* __restrict__ pS, const float* __restrict__ pT,
                   const unsigned short* __restrict__ wm,
                   float* __restrict__ acc) {
    const int b = blockIdx.x & 1;
    int tid8 = (blockIdx.x >> 1) * 128 + threadIdx.x;    // < NV8 exactly
    int v8 = tid8 * 8;
    int d = v8 % DIM;                                    // multiple of 8
    int t1 = v8 / DIM;
    int w = t1 % DIM;
    int h = t1 / DIM;

    const float* sS = pS + (size_t)b * NC * NV + v8;
    const float* sT = pT + (size_t)b * NC * NV + v8;
    const unsigned short* w0 = wm + (size_t)b * PADV;

    int off = (h + 1) * HS2 + (w + 1) * WS2 + (d + 8);
    uint4 M0 = *(const uint4*)(w0 + off - HS2);
    uint4 M1 = *(const uint4*)(w0 + off);
    uint4 M2 = *(const uint4*)(w0 + off + HS2);
    uint4 MM;
    MM.x = M0.x | M1.x | M2.x;
    MM.y = M0.y | M1.y | M2.y;
    MM.z = M0.z | M1.z | M2.z;
    MM.w = M0.w | M1.w | M2.w;
    unsigned mk[8];
    mk[0] = MM.x & 0xFFFFu; mk[1] = MM.x >> 16;
    mk[2] = MM.y & 0xFFFFu; mk[3] = MM.y >> 16;
    mk[4] = MM.z & 0xFFFFu; mk[5] = MM.z >> 16;
    mk[6] = MM.w & 0xFFFFu; mk[7] = MM.w >> 16;

    float4 seSA = {0,0,0,0}, seTA = {0,0,0,0}, dotA = {0,0,0,0};
    float4 seSB = {0,0,0,0}, seTB = {0,0,0,0}, dotB = {0,0,0,0};
#pragma unroll
    for (int c = 0; c < NC; ++c) {
        const float* a = sS + (size_t)c * NV;
        const float* t = sT + (size_t)c * NV;
        float4 vsA = *(const float4*)a;
        float4 vsB = *(const float4*)(a + 4);
        float4 vtA = *(const float4*)t;
        float4 vtB = *(const float4*)(t + 4);
        float e;
        seSA.x += __expf(vsA.x); e = __expf(vtA.x); seTA.x += e; dotA.x += e * (vtA.x - vsA.x);
        seSA.y += __expf(vsA.y); e = __expf(vtA.y); seTA.y += e; dotA.y += e * (vtA.y - vsA.y);
        seSA.z += __expf(vsA.z); e = __expf(vtA.z); seTA.z += e; dotA.z += e * (vtA.z - vsA.z);
        seSA.w += __expf(vsA.w); e = __expf(vtA.w); seTA.w += e; dotA.w += e * (vtA.w - vsA.w);
        seSB.x += __expf(vsB.x); e = __expf(vtB.x); seTB.x += e; dotB.x += e * (vtB.x - vsB.x);
        seSB.y += __expf(vsB.y); e = __expf(vtB.y); seTB.y += e; dotB.y += e * (vtB.y - vsB.y);
        seSB.z += __expf(vsB.z); e = __expf(vtB.z); seTB.z += e; dotB.z += e * (vtB.z - vsB.z);
        seSB.w += __expf(vsB.w); e = __expf(vtB.w); seTB.w += e; dotB.w += e * (vtB.w - vsB.w);
    }
    float pk[8];
    pk[0] = dotA.x / seTA.x + __logf(seSA.x) - __logf(seTA.x);
    pk[1] = dotA.y / seTA.y + __logf(seSA.y) - __logf(seTA.y);
    pk[2] = dotA.z / seTA.z + __logf(seSA.z) - __logf(seTA.z);
    pk[3] = dotA.w / seTA.w + __logf(seSA.w) - __logf(seTA.w);
    pk[4] = dotB.x / seTB.x + __logf(seSB.x) - __logf(seTB.x);
    pk[5] = dotB.y / seTB.y + __logf(seSB.y) - __logf(seTB.y);
    pk[6] = dotB.z / seTB.z + __logf(seSB.z) - __logf(seTB.z);
    pk[7] = dotB.w / seTB.w + __logf(seSB.w) - __logf(seTB.w);

    bool hwint = ((unsigned)(h - 1) <= 93u) && ((unsigned)(w - 1) <= 93u);
    float num[NC], cnt[NC];
#pragma unroll
    for (int c = 0; c < NC; ++c) { num[c] = 0.f; cnt[c] = 0.f; }
#pragma unroll
    for (int j = 0; j < 8; ++j) {
        unsigned m = mk[j];
        // fully-interior uniform window -> box-sum==27 -> not boundary
        if (hwint && ((unsigned)(d + j - 1) <= 93u) && (m & (m - 1)) == 0u) m = 0u;
        float p = pk[j];
#pragma unroll
        for (int c = 0; c < NC; ++c) {
            float hit = (float)((m >> c) & 1u);
            num[c] = fmaf(hit, p, num[c]);
            cnt[c] += hit;
        }
    }

    // wave shfl reduction -> LDS -> global atomics (spread: 16-float stride)
    __shared__ float snum[NC], scnt[NC];
    if (threadIdx.x < NC) { snum[threadIdx.x] = 0.f; scnt[threadIdx.x] = 0.f; }
    __syncthreads();
    int lane = threadIdx.x & 63;
#pragma unroll
    for (int c = 0; c < NC; ++c) {
        float s = num[c], n = cnt[c];
#pragma unroll
        for (int o = 32; o; o >>= 1) {
            s += __shfl_xor(s, o);
            n += __shfl_xor(n, o);
        }
        if (lane == 0) {
            atomicAdd(&snum[c], s);
            atomicAdd(&scnt[c], n);
        }
    }
    __syncthreads();
    if (threadIdx.x < NC) {
        atomicAdd(&acc[(b * NC + threadIdx.x) * 16], snum[threadIdx.x]);
        atomicAdd(&acc[(32 + b * NC + threadIdx.x) * 16], scnt[threadIdx.x]);
    }
}

// ---- Kernel 5: finalize scalar ----
__global__ void finalize_kernel(const float* __restrict__ acc, float* __restrict__ out) {
    if (threadIdx.x == 0 && blockIdx.x == 0) {
        float s = 0.f;
        for (int i = 0; i < 2 * NC; ++i) {
            float n = acc[(32 + i) * 16];
            if (n > 0.f) s += acc[i * 16] / ((float)NC * n);
        }
        out[0] = s;
    }
}

extern "C" void kernel_launch(void* const* d_in, const int* in_sizes, int n_in,
                              void* d_out, int out_size, void* d_ws, size_t ws_size,
                              hipStream_t stream) {
    const float* preds_S = (const float*)d_in[0];
    const float* preds_T = (const float*)d_in[1];
    const float* outputs_T = (const float*)d_in[2];

    // ws layout: [4KB acc (64 slots x 16 floats)][bm SLABB][dm SLABB][wm SLABB]
    char* ws = (char*)d_ws;
    float* acc = (float*)ws;
    unsigned short* bm = (unsigned short*)(ws + 4096);
    unsigned short* dm = (unsigned short*)(ws + 4096 + SLABB);
    unsigned short* wm = (unsigned short*)(ws + 4096 + 2 * SLABB);

    // only acc + bm need zeroing (dm/wm are written before any consumed read)
    hipMemsetAsync(d_ws, 0, 4096 + SLABB, stream);

    argmax_bit_kernel<<<(2 * NV8) / 128, 128, 0, stream>>>(outputs_T, bm);
    {
        int chunks = 2 * PADV / 8;
        int blocks = (chunks + 255) / 256;
        or_d_kernel<<<blocks, 256, 0, stream>>>(bm, dm);
        or_w_kernel<<<blocks, 256, 0, stream>>>(dm, wm);
    }
    boundary_kl_kernel<<<2 * (NV8 / 128), 128, 0, stream>>>(preds_S, preds_T, wm, acc);
    finalize_kernel<<<1, 64, 0, stream>>>(acc, (float*)d_out);
}